// Round 1
// baseline (31.457 us; speedup 1.0000x reference)
//
#include <hip/hip_runtime.h>
#include <math.h>

// DifferentiableLogicLayer:
//   out[b,g] = sum_o ops(a,b)[o] * softmax(gate_logits[g])[o]
//   a = clip(x[b, g % 8192]), b = clip(x[b, (g+1) % 8192])
// All 16 ops are affine in {1, a, b, a*b}  ==>
//   out[b,g] = c0[g] + ca[g]*a + cb[g]*b + cab[g]*a*b
// Memory-bound: 64 MB read (x) + 64 MB write (out). Roofline ~20.5 us.

constexpr int INPUT_SIZE = 8192;
constexpr int NUM_GATES  = 8192;
constexpr int BATCH      = 2048;
constexpr int V4_PER_ROW = INPUT_SIZE / 4;   // 2048 float4 per row

// ---------------------------------------------------------------------------
// Kernel 1: fold softmax(gate_logits) into 4 affine coefficients per gate.
// 8192 gates, one thread each. Output: d_ws as float4[NUM_GATES] = (c0,ca,cb,cab)
// ---------------------------------------------------------------------------
__global__ __launch_bounds__(256) void gate_weights_kernel(
    const float* __restrict__ logits, float4* __restrict__ w) {
    int g = blockIdx.x * blockDim.x + threadIdx.x;
    if (g >= NUM_GATES) return;

    const float4* lp = reinterpret_cast<const float4*>(logits + (size_t)g * 16);
    float4 l0 = lp[0], l1 = lp[1], l2 = lp[2], l3 = lp[3];
    float p[16];
    p[0]=l0.x;  p[1]=l0.y;  p[2]=l0.z;  p[3]=l0.w;
    p[4]=l1.x;  p[5]=l1.y;  p[6]=l1.z;  p[7]=l1.w;
    p[8]=l2.x;  p[9]=l2.y;  p[10]=l2.z; p[11]=l2.w;
    p[12]=l3.x; p[13]=l3.y; p[14]=l3.z; p[15]=l3.w;

    float m = p[0];
    #pragma unroll
    for (int i = 1; i < 16; ++i) m = fmaxf(m, p[i]);
    float s = 0.f;
    #pragma unroll
    for (int i = 0; i < 16; ++i) { p[i] = __expf(p[i] - m); s += p[i]; }
    float inv = 1.f / s;
    #pragma unroll
    for (int i = 0; i < 16; ++i) p[i] *= inv;

    // Coefficients of {1, a, b, ab} for each of the 16 soft ops, dotted with p:
    float c0  = p[8]+p[9]+p[10]+p[11]+p[12]+p[13]+p[14]+p[15];
    float ca  = p[2]+p[3]+p[6]+p[7] - p[8]-p[9]-p[12]-p[13];
    float cb  = p[4]+p[5]+p[6]+p[7] - p[8]-p[9]-p[10]-p[11];
    float cab = p[1]-p[2]-p[4]-2.f*p[6]-p[7]+p[8]+2.f*p[9]+p[11]+p[13]-p[14];

    w[g] = make_float4(c0, ca, cb, cab);
}

// ---------------------------------------------------------------------------
// Kernel 2: main streaming kernel.
// 2048 blocks x 256 threads = 524288 threads. Each thread owns one float4
// column slot (col4 = tid & 2047), hoists its 4 weight-float4s to registers,
// then walks 8 rows (row stride 256). Per row: one float4 load of x, one
// overlapping float4 load for the wrap neighbor (L1 hit), one float4 store.
// ---------------------------------------------------------------------------
__global__ __launch_bounds__(256) void dll_main_kernel(
    const float* __restrict__ x,
    const float4* __restrict__ w,
    float* __restrict__ out) {

    int tid  = blockIdx.x * blockDim.x + threadIdx.x;   // 0 .. 524287
    int col4 = tid & (V4_PER_ROW - 1);                  // fixed column slot
    int row0 = tid >> 11;                               // 0 .. 255

    int g = col4 * 4;
    // Weight table is 128 KB: L2-resident, and these 4 loads happen once.
    float4 w0 = w[g + 0];
    float4 w1 = w[g + 1];
    float4 w2 = w[g + 2];
    float4 w3 = w[g + 3];

    const float4* x4  = reinterpret_cast<const float4*>(x);
    float4*      out4 = reinterpret_cast<float4*>(out);
    int col4n = (col4 + 1) & (V4_PER_ROW - 1);          // wrap within row

    for (int row = row0; row < BATCH; row += 256) {
        size_t base = (size_t)row * V4_PER_ROW;
        float4 xv = x4[base + col4];
        float4 xn = x4[base + col4n];

        float a0 = fminf(fmaxf(xv.x, 0.f), 1.f);
        float a1 = fminf(fmaxf(xv.y, 0.f), 1.f);
        float a2 = fminf(fmaxf(xv.z, 0.f), 1.f);
        float a3 = fminf(fmaxf(xv.w, 0.f), 1.f);
        float a4 = fminf(fmaxf(xn.x, 0.f), 1.f);

        float4 o;
        o.x = fmaf(w0.w, a0 * a1, fmaf(w0.z, a1, fmaf(w0.y, a0, w0.x)));
        o.y = fmaf(w1.w, a1 * a2, fmaf(w1.z, a2, fmaf(w1.y, a1, w1.x)));
        o.z = fmaf(w2.w, a2 * a3, fmaf(w2.z, a3, fmaf(w2.y, a2, w2.x)));
        o.w = fmaf(w3.w, a3 * a4, fmaf(w3.z, a4, fmaf(w3.y, a3, w3.x)));

        out4[base + col4] = o;
    }
}

extern "C" void kernel_launch(void* const* d_in, const int* in_sizes, int n_in,
                              void* d_out, int out_size, void* d_ws, size_t ws_size,
                              hipStream_t stream) {
    const float* x      = reinterpret_cast<const float*>(d_in[0]);
    const float* logits = reinterpret_cast<const float*>(d_in[1]);
    float*       out    = reinterpret_cast<float*>(d_out);
    float4*      w      = reinterpret_cast<float4*>(d_ws);   // 8192 * 16 B = 128 KB

    gate_weights_kernel<<<NUM_GATES / 256, 256, 0, stream>>>(logits, w);

    int total_threads = BATCH / 8 * V4_PER_ROW;               // 524288
    dll_main_kernel<<<total_threads / 256, 256, 0, stream>>>(x, w, out);
}